// Round 3
// baseline (1400.037 us; speedup 1.0000x reference)
//
#include <hip/hip_runtime.h>
#include <hip/hip_bf16.h>
#include <math.h>

static constexpr int BN   = 16384;  // batch rows
static constexpr int NFFT = 512;
static constexpr int NBIN = 257;    // rfft bins
static constexpr int NH   = 128;    // hidden
static constexpr int NE   = 256;    // encoder dim
static constexpr int NG   = 512;    // 4*H gates
static constexpr float EPSF  = 1.1920929e-07f;
static constexpr float LNEPS = 1e-07f;

__device__ __forceinline__ float sigm(float x){ return 1.0f/(1.0f+expf(-x)); }

// ---------------- twiddle tables ----------------
// fwdT[2k][n] = cos(2pi k n/512), fwdT[2k+1][n] = -sin(...)   (layout [514][512])
// invT[n][2k] = w_k cos, invT[n][2k+1] = -w_k sin             (layout [512][514])
__global__ void twiddle_fill(float* __restrict__ fwdT, float* __restrict__ invT){
  int idx = blockIdx.x*blockDim.x + threadIdx.x;
  if (idx >= NBIN*NFFT) return;
  int k = idx >> 9;          // 0..256
  int n = idx & 511;
  int m = (k*n) & 511;       // exact argument reduction
  float th = (float)m * (6.283185307179586f/512.0f);
  float s, c;
  sincosf(th, &s, &c);
  fwdT[(size_t)(2*k)*NFFT + n]   = c;
  fwdT[(size_t)(2*k+1)*NFFT + n] = -s;
  float wk = (k==0 || k==256) ? (1.0f/512.0f) : (2.0f/512.0f);
  invT[(size_t)n*514 + 2*k]     = wk*c;
  invT[(size_t)n*514 + 2*k + 1] = -wk*s;
}

// ---------------- generic NT GEMM (all fp32) ----------------
// C[row][col] = sum_k A[row][k]*B[col][k]  (+ optional second pair A2/B2, + biases)
#define TILE 64
#define TKK  16
#define LDP  68   // padded LDS pitch (68%32=4 -> 2-way conflict = free)

__device__ __forceinline__ void gemm_phase(
    const float* __restrict__ A, int lda,
    const float* __restrict__ B, int ldb, int K,
    int row0, int col0, int M, int tid,
    float (&acc)[4][4], float (*As)[LDP], float (*Bs)[LDP])
{
  const int lk = tid & 15;
  const int lr = tid >> 4;
  const int tx = tid & 15;
  const int ty = tid >> 4;
  const int ktiles = (K + TKK - 1) / TKK;
  for (int kt = 0; kt < ktiles; ++kt) {
    const int kk = kt*TKK + lk;
    const bool kok = (kk < K);
    #pragma unroll
    for (int r = 0; r < 4; ++r) {
      const int rr = lr + r*16;
      As[lk][rr] = kok ? A[(size_t)(row0+rr)*lda + kk] : 0.0f;
      const int bj = col0 + rr;
      Bs[lk][rr] = (kok && bj < M) ? B[(size_t)bj*ldb + kk] : 0.0f;
    }
    __syncthreads();
    #pragma unroll
    for (int q = 0; q < TKK; ++q) {
      const float4 av = *reinterpret_cast<const float4*>(&As[q][ty*4]);
      const float4 bv = *reinterpret_cast<const float4*>(&Bs[q][tx*4]);
      const float a[4] = {av.x, av.y, av.z, av.w};
      const float b[4] = {bv.x, bv.y, bv.z, bv.w};
      #pragma unroll
      for (int i = 0; i < 4; ++i)
        #pragma unroll
        for (int j = 0; j < 4; ++j)
          acc[i][j] = fmaf(a[i], b[j], acc[i][j]);
    }
    __syncthreads();
  }
}

__global__ __launch_bounds__(256)
void gemm_nt(const float* __restrict__ A, int lda,
             const float* __restrict__ B, int ldb, int K,
             const float* __restrict__ A2, int lda2,
             const float* __restrict__ B2, int ldb2, int K2,
             const float* __restrict__ bias1,
             const float* __restrict__ bias2,
             float* __restrict__ Cout, int ldc, int M)
{
  __shared__ __align__(16) float As[TKK][LDP];
  __shared__ __align__(16) float Bs[TKK][LDP];
  const int tid  = threadIdx.x;
  const int row0 = blockIdx.x * TILE;
  const int col0 = blockIdx.y * TILE;
  float acc[4][4] = {};
  gemm_phase(A, lda, B, ldb, K, row0, col0, M, tid, acc, As, Bs);
  if (A2)
    gemm_phase(A2, lda2, B2, ldb2, K2, row0, col0, M, tid, acc, As, Bs);
  const int tx = tid & 15, ty = tid >> 4;
  #pragma unroll
  for (int i = 0; i < 4; ++i) {
    const int row = row0 + ty*4 + i;
    #pragma unroll
    for (int j = 0; j < 4; ++j) {
      const int col = col0 + tx*4 + j;
      if (col < M) {
        float v = acc[i][j];
        if (bias1) v += bias1[col];
        if (bias2) v += bias2[col];
        Cout[(size_t)row*ldc + col] = v;
      }
    }
  }
}

// ---------------- elementwise kernels ----------------
// RI[n][2k]=re, [2k+1]=im  ->  MAG[n][k]; RI overwritten with (cos phi, sin phi)
__global__ void magphase_kernel(float* __restrict__ RI, float* __restrict__ MAG){
  int idx = blockIdx.x*blockDim.x + threadIdx.x;
  if (idx >= BN*NBIN) return;
  int n = idx / NBIN;
  int k = idx - n*NBIN;
  size_t p = (size_t)n*514 + 2*k;
  float r  = RI[p];
  float im = RI[p+1];
  MAG[idx] = sqrtf(fmaxf(r*r + im*im, EPSF));
  float re = r + EPSF, ie = im + EPSF;
  float hyp = sqrtf(re*re + ie*ie);
  hyp = fmaxf(hyp, 1e-35f);
  RI[p]   = re/hyp;    // cos(atan2(ie,re))
  RI[p+1] = ie/hyp;    // sin(atan2(ie,re))
}

// in_state (2,BN,NH,2) f32 -> fp32 h1,c1,h2,c2 planes
__global__ void unpack_state(const float* __restrict__ st,
                             float* __restrict__ h1, float* __restrict__ c1,
                             float* __restrict__ h2, float* __restrict__ c2){
  int idx = blockIdx.x*blockDim.x + threadIdx.x;
  if (idx >= BN*NH) return;
  h1[idx] = st[(size_t)idx*2];
  c1[idx] = st[(size_t)idx*2+1];
  size_t off = (size_t)BN*NH*2;
  h2[idx] = st[off + (size_t)idx*2];
  c2[idx] = st[off + (size_t)idx*2+1];
}

// gates G[n][0:512] (i,f,g,o) + prev c -> new h,c (fp32 scratch + f32 out_state)
__global__ void lstm_cell(const float* __restrict__ G,
                          float* __restrict__ h, float* __restrict__ c,
                          float* __restrict__ ost){
  int idx = blockIdx.x*blockDim.x + threadIdx.x;
  if (idx >= BN*NH) return;
  int n = idx >> 7, j = idx & 127;
  const float* g = G + (size_t)n*NG;
  float gi = g[j], gf = g[NH+j], gc = g[2*NH+j], go = g[3*NH+j];
  float cp = c[idx];
  float cn = sigm(gf)*cp + sigm(gi)*tanhf(gc);
  float hn = sigm(go)*tanhf(cn);
  h[idx] = hn; c[idx] = cn;
  ost[(size_t)idx*2]   = hn;
  ost[(size_t)idx*2+1] = cn;
}

// S[n][2k] = sigmoid(Mpre)*mag*cphi ; S[n][2k+1] = ...*sphi   (in place over RI)
__global__ void est_build(const float* __restrict__ Mpre,
                          const float* __restrict__ MAG,
                          float* __restrict__ RI){
  int idx = blockIdx.x*blockDim.x + threadIdx.x;
  if (idx >= BN*NBIN) return;
  int n = idx / NBIN;
  int k = idx - n*NBIN;
  float e = sigm(Mpre[idx]) * MAG[idx];
  size_t p = (size_t)n*514 + 2*k;
  RI[p]   *= e;
  RI[p+1] *= e;
}

// LayerNorm over 256, one wave per row
__global__ void ln_kernel(const float* __restrict__ ENC,
                          const float* __restrict__ gamma,
                          const float* __restrict__ beta,
                          float* __restrict__ OUT){
  int row = blockIdx.x;
  int t = threadIdx.x;               // 64 threads
  const float* e = ENC + (size_t)row*NE;
  float v[4];
  float s = 0.f;
  #pragma unroll
  for (int i=0;i<4;++i){ v[i] = e[t + 64*i]; s += v[i]; }
  #pragma unroll
  for (int off=32; off>=1; off>>=1) s += __shfl_xor(s, off, 64);
  float mean = s * (1.0f/NE);
  float d[4];
  float ss = 0.f;
  #pragma unroll
  for (int i=0;i<4;++i){ d[i] = v[i]-mean; ss += d[i]*d[i]; }
  #pragma unroll
  for (int off=32; off>=1; off>>=1) ss += __shfl_xor(ss, off, 64);
  float inv = 1.0f / sqrtf(ss*(1.0f/NE) + LNEPS);
  float* o = OUT + (size_t)row*NE;
  #pragma unroll
  for (int i=0;i<4;++i){
    int col = t + 64*i;
    o[col] = d[i]*inv*gamma[col] + beta[col];
  }
}

// D = sigmoid(mask2pre) * ENC
__global__ void dec_in(const float* __restrict__ Mpre,
                       const float* __restrict__ ENC,
                       float* __restrict__ D){
  int idx = blockIdx.x*blockDim.x + threadIdx.x;
  if (idx >= BN*NE) return;
  D[idx] = sigm(Mpre[idx]) * ENC[idx];
}

// ---------------- launch ----------------
extern "C" void kernel_launch(void* const* d_in, const int* in_sizes, int n_in,
                              void* d_out, int out_size, void* d_ws, size_t ws_size,
                              hipStream_t stream)
{
  const float* x       = (const float*)d_in[0];
  const float* st1     = (const float*)d_in[1];
  const float* st2     = (const float*)d_in[2];
  const float* s1_wih1 = (const float*)d_in[3];
  const float* s1_whh1 = (const float*)d_in[4];
  const float* s1_bih1 = (const float*)d_in[5];
  const float* s1_bhh1 = (const float*)d_in[6];
  const float* s1_wih2 = (const float*)d_in[7];
  const float* s1_whh2 = (const float*)d_in[8];
  const float* s1_bih2 = (const float*)d_in[9];
  const float* s1_bhh2 = (const float*)d_in[10];
  const float* s1_dw   = (const float*)d_in[11];
  const float* s1_db   = (const float*)d_in[12];
  const float* enc_w   = (const float*)d_in[13];
  const float* ln_g    = (const float*)d_in[14];
  const float* ln_b    = (const float*)d_in[15];
  const float* s2_wih1 = (const float*)d_in[16];
  const float* s2_whh1 = (const float*)d_in[17];
  const float* s2_bih1 = (const float*)d_in[18];
  const float* s2_bhh1 = (const float*)d_in[19];
  const float* s2_wih2 = (const float*)d_in[20];
  const float* s2_whh2 = (const float*)d_in[21];
  const float* s2_bih2 = (const float*)d_in[22];
  const float* s2_bhh2 = (const float*)d_in[23];
  const float* s2_dw   = (const float*)d_in[24];
  const float* s2_db   = (const float*)d_in[25];
  const float* dec_w   = (const float*)d_in[26];

  float* out_dec = (float*)d_out;                      // (BN,512,1) f32
  float* out_st1 = out_dec + (size_t)BN*NFFT;          // (2,BN,128,2) f32
  float* out_st2 = out_st1 + (size_t)2*BN*NH*2;        // (2,BN,128,2) f32

  // Workspace (aliased; ~114 MiB):
  //   RI (BN x 514): re/im -> cos/sin phi -> est stft; later ENC + ENCN live here
  //   G  (BN x 512): gates / mask-pre; later Y1 lives here
  float* ws = (float*)d_ws;
  size_t o = 0;
  float* fwdT = ws + o; o += (size_t)514*512;
  float* invT = ws + o; o += (size_t)512*514;
  float* RI   = ws + o; o += (size_t)BN*514;
  float* MAG  = ws + o; o += (size_t)BN*NBIN;
  float* G    = ws + o; o += (size_t)BN*NG;
  float* H1   = ws + o; o += (size_t)BN*NH;
  float* C1   = ws + o; o += (size_t)BN*NH;
  float* H2   = ws + o; o += (size_t)BN*NH;
  float* C2   = ws + o; o += (size_t)BN*NH;
  float* Y1   = G;               // irfft output reuses G (mask1-pre consumed)
  float* ENC  = RI;              // encoder output reuses RI (est-stft consumed)
  float* ENCN = RI + (size_t)BN*NE;  // enc_n / dec-input, fits in RI's 514-wide span
  (void)ws_size; (void)in_sizes; (void)n_in; (void)out_size;

  const dim3 blk(256);
  const int eNH   = (BN*NH   + 255)/256;
  const int eNBIN = (BN*NBIN + 255)/256;
  const int eNE   = (BN*NE   + 255)/256;

  // twiddles
  twiddle_fill<<<(NBIN*NFFT+255)/256, blk, 0, stream>>>(fwdT, invT);

  // rfft: RI = x @ fwdT^T   [BN x 514]
  dim3 g_fft(BN/TILE, (514+TILE-1)/TILE);
  gemm_nt<<<g_fft, blk, 0, stream>>>(x, NFFT, fwdT, NFFT, NFFT,
      nullptr, 0, nullptr, 0, 0, nullptr, nullptr, RI, 514, 514);

  magphase_kernel<<<eNBIN, blk, 0, stream>>>(RI, MAG);
  unpack_state<<<eNH, blk, 0, stream>>>(st1, H1, C1, H2, C2);

  // ---- sep block 1 ----
  dim3 g_g(BN/TILE, NG/TILE);
  gemm_nt<<<g_g, blk, 0, stream>>>(MAG, NBIN, s1_wih1, NBIN, NBIN,
      H1, NH, s1_whh1, NH, NH, s1_bih1, s1_bhh1, G, NG, NG);
  lstm_cell<<<eNH, blk, 0, stream>>>(G, H1, C1, out_st1);
  gemm_nt<<<g_g, blk, 0, stream>>>(H1, NH, s1_wih2, NH, NH,
      H2, NH, s1_whh2, NH, NH, s1_bih2, s1_bhh2, G, NG, NG);
  lstm_cell<<<eNH, blk, 0, stream>>>(G, H2, C2, out_st1 + (size_t)BN*NH*2);
  dim3 g_m1(BN/TILE, (NBIN+TILE-1)/TILE);
  gemm_nt<<<g_m1, blk, 0, stream>>>(H2, NH, s1_dw, NH, NH,
      nullptr, 0, nullptr, 0, 0, s1_db, nullptr, G, NBIN, NBIN);
  est_build<<<eNBIN, blk, 0, stream>>>(G, MAG, RI);

  // irfft: Y1 = S @ invT^T  [BN x 512]   (Y1 aliases G; mask1-pre fully consumed)
  dim3 g_ifft(BN/TILE, NFFT/TILE);
  gemm_nt<<<g_ifft, blk, 0, stream>>>(RI, 514, invT, 514, 514,
      nullptr, 0, nullptr, 0, 0, nullptr, nullptr, Y1, NFFT, NFFT);

  // encoder + LN   (ENC aliases RI; est-stft fully consumed)
  dim3 g_enc(BN/TILE, NE/TILE);
  gemm_nt<<<g_enc, blk, 0, stream>>>(Y1, NFFT, enc_w, NFFT, NFFT,
      nullptr, 0, nullptr, 0, 0, nullptr, nullptr, ENC, NE, NE);
  ln_kernel<<<BN, 64, 0, stream>>>(ENC, ln_g, ln_b, ENCN);

  // ---- sep block 2 ----
  unpack_state<<<eNH, blk, 0, stream>>>(st2, H1, C1, H2, C2);
  gemm_nt<<<g_g, blk, 0, stream>>>(ENCN, NE, s2_wih1, NE, NE,
      H1, NH, s2_whh1, NH, NH, s2_bih1, s2_bhh1, G, NG, NG);
  lstm_cell<<<eNH, blk, 0, stream>>>(G, H1, C1, out_st2);
  gemm_nt<<<g_g, blk, 0, stream>>>(H1, NH, s2_wih2, NH, NH,
      H2, NH, s2_whh2, NH, NH, s2_bih2, s2_bhh2, G, NG, NG);
  lstm_cell<<<eNH, blk, 0, stream>>>(G, H2, C2, out_st2 + (size_t)BN*NH*2);
  gemm_nt<<<g_enc, blk, 0, stream>>>(H2, NH, s2_dw, NH, NH,
      nullptr, 0, nullptr, 0, 0, s2_db, nullptr, G, NE, NE);

  // decoded = (sigmoid(mask2pre)*ENC) @ dec_w^T  -> f32 out
  dec_in<<<eNE, blk, 0, stream>>>(G, ENC, ENCN);
  dim3 g_dec(BN/TILE, NFFT/TILE);
  gemm_nt<<<g_dec, blk, 0, stream>>>(ENCN, NE, dec_w, NE, NE,
      nullptr, 0, nullptr, 0, 0, nullptr, nullptr, out_dec, NFFT, NFFT);
}

// Round 4
// 647.966 us; speedup vs baseline: 2.1607x; 2.1607x over previous
//
#include <hip/hip_runtime.h>
#include <hip/hip_bf16.h>
#include <math.h>

static constexpr int BN   = 16384;
static constexpr int NFFT = 512;
static constexpr int NBIN = 257;
static constexpr int NH   = 128;
static constexpr int NE   = 256;
static constexpr int NG   = 512;
static constexpr float EPSF  = 1.1920929e-07f;
static constexpr float LNEPS = 1e-07f;

using short8  = __attribute__((ext_vector_type(8))) short;
using float4v = __attribute__((ext_vector_type(4))) float;

__device__ __forceinline__ float sigm(float x){ return 1.0f/(1.0f+expf(-x)); }
__device__ __forceinline__ ushort f2b(float v){
  __hip_bfloat16 b = __float2bfloat16(v);
  return *reinterpret_cast<ushort*>(&b);
}
__device__ __forceinline__ float b2f(ushort u){
  __hip_bfloat16 b = *reinterpret_cast<__hip_bfloat16*>(&u);
  return __bfloat162float(b);
}
__device__ __forceinline__ void split(float v, ushort* hi, ushort* lo){
  ushort h = f2b(v);
  *hi = h;
  *lo = f2b(v - b2f(h));
}

// ================= MFMA bf16x2 NT GEMM =================
// C[row][col] = sum_k A[row][k]*B[col][k] (+ optional phase2 A2/B2) + bias
// A planes: [16384][lda] bf16 hi/lo. B planes: [Mp][K] (ld == K). All dims padded:
// K mult of 32, Mp mult of 128. C: f32 (ldc) or hi/lo bf16 planes.
__global__ __launch_bounds__(256)
void mfma_gemm(const ushort* __restrict__ Ahi, const ushort* __restrict__ Alo,
               int lda, int K,
               const ushort* __restrict__ Bhi, const ushort* __restrict__ Blo,
               const ushort* __restrict__ A2hi, const ushort* __restrict__ A2lo,
               int lda2, int K2,
               const ushort* __restrict__ B2hi, const ushort* __restrict__ B2lo,
               const float* __restrict__ bias,
               float* __restrict__ C, ushort* __restrict__ Chi,
               ushort* __restrict__ Clo, int ldc)
{
  __shared__ ushort As[128][72];   // [row][k0..31 hi | k0..31 lo | pad]
  __shared__ ushort Bs[128][72];
  const int tid  = threadIdx.x;
  const int row0 = blockIdx.x * 128;
  const int col0 = blockIdx.y * 128;
  const int lane = tid & 63;
  const int wv   = tid >> 6;
  const int wr   = (wv >> 1) * 64;   // wave row offset in tile
  const int wc   = (wv & 1) * 64;    // wave col offset in tile
  const int fr   = lane & 15;
  const int quad = lane >> 4;

  float4v acc[4][4];
  #pragma unroll
  for (int i = 0; i < 4; ++i)
    #pragma unroll
    for (int j = 0; j < 4; ++j)
      acc[i][j] = float4v{0.f, 0.f, 0.f, 0.f};

  #pragma unroll 1
  for (int phase = 0; phase < 2; ++phase) {
    const ushort* pAhi = phase ? A2hi : Ahi;
    const ushort* pAlo = phase ? A2lo : Alo;
    const ushort* pBhi = phase ? B2hi : Bhi;
    const ushort* pBlo = phase ? B2lo : Blo;
    const int ld_a = phase ? lda2 : lda;
    const int KK   = phase ? K2 : K;
    if (!pAhi) continue;
    for (int kt = 0; kt < KK / 32; ++kt) {
      // ---- stage 128x32 hi/lo tiles of A and B ----
      #pragma unroll
      for (int s = 0; s < 2; ++s) {
        const int c   = s * 256 + tid;   // 0..511
        const int row = c >> 2;
        const int kc  = c & 3;
        const size_t ga = (size_t)(row0 + row) * ld_a + kt * 32 + kc * 8;
        *(short8*)&As[row][kc * 8]      = *(const short8*)(pAhi + ga);
        *(short8*)&As[row][32 + kc * 8] = *(const short8*)(pAlo + ga);
        const size_t gb = (size_t)(col0 + row) * KK + kt * 32 + kc * 8;
        *(short8*)&Bs[row][kc * 8]      = *(const short8*)(pBhi + gb);
        *(short8*)&Bs[row][32 + kc * 8] = *(const short8*)(pBlo + gb);
      }
      __syncthreads();
      // ---- fragments ----
      short8 ah[4], al[4], bh[4], bl[4];
      #pragma unroll
      for (int i = 0; i < 4; ++i) {
        ah[i] = *(const short8*)&As[wr + i * 16 + fr][quad * 8];
        al[i] = *(const short8*)&As[wr + i * 16 + fr][32 + quad * 8];
        bh[i] = *(const short8*)&Bs[wc + i * 16 + fr][quad * 8];
        bl[i] = *(const short8*)&Bs[wc + i * 16 + fr][32 + quad * 8];
      }
      #pragma unroll
      for (int i = 0; i < 4; ++i)
        #pragma unroll
        for (int j = 0; j < 4; ++j) {
          acc[i][j] = __builtin_amdgcn_mfma_f32_16x16x32_bf16(ah[i], bh[j], acc[i][j], 0, 0, 0);
          acc[i][j] = __builtin_amdgcn_mfma_f32_16x16x32_bf16(ah[i], bl[j], acc[i][j], 0, 0, 0);
          acc[i][j] = __builtin_amdgcn_mfma_f32_16x16x32_bf16(al[i], bh[j], acc[i][j], 0, 0, 0);
        }
      __syncthreads();
    }
  }

  // ---- epilogue: C/D layout col=lane&15, row=quad*4+reg ----
  #pragma unroll
  for (int j = 0; j < 4; ++j) {
    const int colb = col0 + wc + j * 16 + fr;
    const float bv = bias ? bias[colb] : 0.f;
    #pragma unroll
    for (int i = 0; i < 4; ++i) {
      #pragma unroll
      for (int r = 0; r < 4; ++r) {
        const int row = row0 + wr + i * 16 + quad * 4 + r;
        const float v = acc[i][j][r] + bv;
        const size_t idx = (size_t)row * ldc + colb;
        if (C) C[idx] = v;
        else   split(v, &Chi[idx], &Clo[idx]);
      }
    }
  }
}

// ================= weight / bias prep =================
__global__ void wconv(const float* __restrict__ src, int M0, int K0,
                      ushort* __restrict__ hi, ushort* __restrict__ lo,
                      int Mp, int Kp){
  int idx = blockIdx.x * blockDim.x + threadIdx.x;
  if (idx >= Mp * Kp) return;
  int r = idx / Kp, c = idx - r * Kp;
  float v = (r < M0 && c < K0) ? src[(size_t)r * K0 + c] : 0.f;
  split(v, &hi[idx], &lo[idx]);
}

__global__ void bias_pad(const float* __restrict__ s1, const float* __restrict__ s2,
                         int L, float* __restrict__ dst, int Lp){
  int idx = blockIdx.x * blockDim.x + threadIdx.x;
  if (idx >= Lp) return;
  float v = 0.f;
  if (idx < L) { v = s1[idx]; if (s2) v += s2[idx]; }
  dst[idx] = v;
}

// fwdT planes [512 cols][512 n]: col c=2k -> cos(2pi k n/512), c=2k+1 -> -sin. k=0..255.
__global__ void fill_fwd(ushort* __restrict__ hi, ushort* __restrict__ lo){
  int idx = blockIdx.x * blockDim.x + threadIdx.x;
  if (idx >= 512 * 512) return;
  int c = idx >> 9, n = idx & 511;
  int k = c >> 1, m = (k * n) & 511;
  float th = (float)m * (6.283185307179586f / 512.0f);
  float s, co; sincosf(th, &s, &co);
  float v = (c & 1) ? -s : co;
  split(v, &hi[idx], &lo[idx]);
}

// invT planes [512 n][544 c]: c=2k -> w_k cos, c=2k+1 -> -w_k sin (k<256);
// c=512 -> Nyquist (+/-1)/512; c=513..543 -> 0
__global__ void fill_inv(ushort* __restrict__ hi, ushort* __restrict__ lo){
  int idx = blockIdx.x * blockDim.x + threadIdx.x;
  if (idx >= 512 * 544) return;
  int n = idx / 544, c = idx - n * 544;
  float v = 0.f;
  if (c < 512) {
    int k = c >> 1, m = (k * n) & 511;
    float th = (float)m * (6.283185307179586f / 512.0f);
    float s, co; sincosf(th, &s, &co);
    float w = (k == 0) ? (1.0f / 512.0f) : (2.0f / 512.0f);
    v = (c & 1) ? -w * s : w * co;
  } else if (c == 512) {
    v = ((n & 1) ? -1.0f : 1.0f) / 512.0f;
  }
  split(v, &hi[idx], &lo[idx]);
}

// ================= elementwise =================
// x f32 [16384][512] -> hi/lo planes [16384][544] (cols 512.. zero)
__global__ void convert_x(const float* __restrict__ x,
                          ushort* __restrict__ hi, ushort* __restrict__ lo){
  int idx = blockIdx.x * blockDim.x + threadIdx.x;
  if (idx >= BN * 544) return;
  int r = idx / 544, c = idx - r * 544;
  float v = (c < 512) ? x[(size_t)r * 512 + c] : 0.f;
  split(v, &hi[idx], &lo[idx]);
}

// Nyquist bin: RI[n][512] = sum x[n][i]*(-1)^i ; RI[n][513] = 0
__global__ void nyq_kernel(const float* __restrict__ x, float* __restrict__ RI){
  int row  = blockIdx.x * 4 + (threadIdx.x >> 6);
  int lane = threadIdx.x & 63;
  const float* xr = x + (size_t)row * 512;
  float s = 0.f;
  #pragma unroll
  for (int i = 0; i < 8; ++i) {
    int n = lane + 64 * i;
    float v = xr[n];
    s += (n & 1) ? -v : v;
  }
  #pragma unroll
  for (int off = 32; off >= 1; off >>= 1) s += __shfl_xor(s, off, 64);
  if (lane == 0) {
    RI[(size_t)row * 514 + 512] = s;
    RI[(size_t)row * 514 + 513] = 0.f;
  }
}

// mag planes [16384][288] from RI f32 [16384][514]
__global__ void magphase_kernel(const float* __restrict__ RI,
                                ushort* __restrict__ mhi, ushort* __restrict__ mlo){
  int idx = blockIdx.x * blockDim.x + threadIdx.x;
  if (idx >= BN * 288) return;
  int n = idx / 288, j = idx - n * 288;
  float mag = 0.f;
  if (j < NBIN) {
    float r  = RI[(size_t)n * 514 + 2 * j];
    float im = RI[(size_t)n * 514 + 2 * j + 1];
    mag = sqrtf(fmaxf(r * r + im * im, EPSF));
  }
  split(mag, &mhi[idx], &mlo[idx]);
}

// in_state (2,BN,NH,2) f32 -> H hi/lo planes + C f32 (both layers)
__global__ void unpack_state(const float* __restrict__ st,
                             ushort* __restrict__ h1hi, ushort* __restrict__ h1lo,
                             float* __restrict__ c1,
                             ushort* __restrict__ h2hi, ushort* __restrict__ h2lo,
                             float* __restrict__ c2){
  int idx = blockIdx.x * blockDim.x + threadIdx.x;
  if (idx >= BN * NH) return;
  split(st[(size_t)idx * 2], &h1hi[idx], &h1lo[idx]);
  c1[idx] = st[(size_t)idx * 2 + 1];
  size_t off = (size_t)BN * NH * 2;
  split(st[off + (size_t)idx * 2], &h2hi[idx], &h2lo[idx]);
  c2[idx] = st[off + (size_t)idx * 2 + 1];
}

// gates G[n][512] + c -> h (hi/lo planes), c (f32), out_state f32 (h,c interleaved)
__global__ void lstm_cell(const float* __restrict__ G,
                          float* __restrict__ c,
                          ushort* __restrict__ hhi, ushort* __restrict__ hlo,
                          float* __restrict__ ost){
  int idx = blockIdx.x * blockDim.x + threadIdx.x;
  if (idx >= BN * NH) return;
  int n = idx >> 7, j = idx & 127;
  const float* g = G + (size_t)n * NG;
  float gi = g[j], gf = g[NH + j], gc = g[2 * NH + j], go = g[3 * NH + j];
  float cp = c[idx];
  float cn = sigm(gf) * cp + sigm(gi) * tanhf(gc);
  float hn = sigm(go) * tanhf(cn);
  c[idx] = cn;
  split(hn, &hhi[idx], &hlo[idx]);
  ost[(size_t)idx * 2]     = hn;
  ost[(size_t)idx * 2 + 1] = cn;
}

// est stft -> S hi/lo planes [16384][544] (pairs; j>=257 zero)
__global__ void est_build(const float* __restrict__ Mpre, int ldm,
                          const ushort* __restrict__ mhi, const ushort* __restrict__ mlo,
                          const float* __restrict__ RI,
                          ushort* __restrict__ shi, ushort* __restrict__ slo){
  int idx = blockIdx.x * blockDim.x + threadIdx.x;
  if (idx >= BN * 272) return;
  int n = idx / 272, j = idx - n * 272;
  float cr = 0.f, ci = 0.f;
  if (j < NBIN) {
    float m   = sigm(Mpre[(size_t)n * ldm + j]);
    float mag = b2f(mhi[(size_t)n * 288 + j]) + b2f(mlo[(size_t)n * 288 + j]);
    float e   = m * mag;
    float r   = RI[(size_t)n * 514 + 2 * j];
    float im  = RI[(size_t)n * 514 + 2 * j + 1];
    float re = r + EPSF, ie = im + EPSF;
    float hyp = fmaxf(sqrtf(re * re + ie * ie), 1e-35f);
    cr = e * re / hyp;
    ci = e * ie / hyp;
  }
  size_t p = (size_t)n * 544 + 2 * j;
  split(cr, &shi[p], &slo[p]);
  split(ci, &shi[p + 1], &slo[p + 1]);
}

// LayerNorm over 256 -> ENCN hi/lo planes
__global__ void ln_kernel(const float* __restrict__ ENC,
                          const float* __restrict__ gamma,
                          const float* __restrict__ beta,
                          ushort* __restrict__ ohi, ushort* __restrict__ olo){
  int row = blockIdx.x;
  int t = threadIdx.x;   // 64
  const float* e = ENC + (size_t)row * NE;
  float v[4]; float s = 0.f;
  #pragma unroll
  for (int i = 0; i < 4; ++i) { v[i] = e[t + 64 * i]; s += v[i]; }
  #pragma unroll
  for (int off = 32; off >= 1; off >>= 1) s += __shfl_xor(s, off, 64);
  float mean = s * (1.0f / NE);
  float d[4]; float ss = 0.f;
  #pragma unroll
  for (int i = 0; i < 4; ++i) { d[i] = v[i] - mean; ss += d[i] * d[i]; }
  #pragma unroll
  for (int off = 32; off >= 1; off >>= 1) ss += __shfl_xor(ss, off, 64);
  float inv = 1.0f / sqrtf(ss * (1.0f / NE) + LNEPS);
  #pragma unroll
  for (int i = 0; i < 4; ++i) {
    int col = t + 64 * i;
    float o = d[i] * inv * gamma[col] + beta[col];
    size_t p = (size_t)row * NE + col;
    split(o, &ohi[p], &olo[p]);
  }
}

// D = sigmoid(mask2pre) * ENC -> hi/lo planes
__global__ void dec_in(const float* __restrict__ Mpre,
                       const float* __restrict__ ENC,
                       ushort* __restrict__ dhi, ushort* __restrict__ dlo){
  int idx = blockIdx.x * blockDim.x + threadIdx.x;
  if (idx >= BN * NE) return;
  int n = idx >> 8, j = idx & 255;
  float v = sigm(Mpre[(size_t)n * 512 + j]) * ENC[idx];
  split(v, &dhi[idx], &dlo[idx]);
}

// ================= launch =================
extern "C" void kernel_launch(void* const* d_in, const int* in_sizes, int n_in,
                              void* d_out, int out_size, void* d_ws, size_t ws_size,
                              hipStream_t stream)
{
  const float* x       = (const float*)d_in[0];
  const float* st1     = (const float*)d_in[1];
  const float* st2     = (const float*)d_in[2];
  const float* s1_wih1 = (const float*)d_in[3];
  const float* s1_whh1 = (const float*)d_in[4];
  const float* s1_bih1 = (const float*)d_in[5];
  const float* s1_bhh1 = (const float*)d_in[6];
  const float* s1_wih2 = (const float*)d_in[7];
  const float* s1_whh2 = (const float*)d_in[8];
  const float* s1_bih2 = (const float*)d_in[9];
  const float* s1_bhh2 = (const float*)d_in[10];
  const float* s1_dw   = (const float*)d_in[11];
  const float* s1_db   = (const float*)d_in[12];
  const float* enc_w   = (const float*)d_in[13];
  const float* ln_g    = (const float*)d_in[14];
  const float* ln_b    = (const float*)d_in[15];
  const float* s2_wih1 = (const float*)d_in[16];
  const float* s2_whh1 = (const float*)d_in[17];
  const float* s2_bih1 = (const float*)d_in[18];
  const float* s2_bhh1 = (const float*)d_in[19];
  const float* s2_wih2 = (const float*)d_in[20];
  const float* s2_whh2 = (const float*)d_in[21];
  const float* s2_bih2 = (const float*)d_in[22];
  const float* s2_bhh2 = (const float*)d_in[23];
  const float* s2_dw   = (const float*)d_in[24];
  const float* s2_db   = (const float*)d_in[25];
  const float* dec_w   = (const float*)d_in[26];

  float* out_dec = (float*)d_out;
  float* out_st1 = out_dec + (size_t)BN * NFFT;
  float* out_st2 = out_st1 + (size_t)2 * BN * NH * 2;

  // ---- workspace (byte bump allocator, 256B aligned) ----
  char* base = (char*)d_ws;
  size_t off = 0;
  auto alloc = [&](size_t bytes) -> void* {
    off = (off + 255) & ~(size_t)255;
    void* p = base + off;
    off += bytes;
    return p;
  };
  ushort* fwdThi = (ushort*)alloc((size_t)512 * 512 * 2);
  ushort* fwdTlo = (ushort*)alloc((size_t)512 * 512 * 2);
  ushort* invThi = (ushort*)alloc((size_t)512 * 544 * 2);
  ushort* invTlo = (ushort*)alloc((size_t)512 * 544 * 2);
  ushort* XShi   = (ushort*)alloc((size_t)BN * 544 * 2);  // x planes, later est-stft planes
  ushort* XSlo   = (ushort*)alloc((size_t)BN * 544 * 2);
  float*  RI     = (float*) alloc((size_t)BN * 514 * 4);
  float*  G      = (float*) alloc((size_t)BN * 512 * 4);  // gates / mask-pre; later Y1 planes
  char*   R1     = (char*)  alloc((size_t)BN * NE * 4 * 2); // MAG planes, later ENC + ENCN
  ushort* h1hi   = (ushort*)alloc((size_t)BN * NH * 2);
  ushort* h1lo   = (ushort*)alloc((size_t)BN * NH * 2);
  ushort* h2hi   = (ushort*)alloc((size_t)BN * NH * 2);
  ushort* h2lo   = (ushort*)alloc((size_t)BN * NH * 2);
  float*  C1     = (float*) alloc((size_t)BN * NH * 4);
  float*  C2     = (float*) alloc((size_t)BN * NH * 4);
  // weight planes
  ushort* w11hi = (ushort*)alloc((size_t)512*288*2); ushort* w11lo = (ushort*)alloc((size_t)512*288*2);
  ushort* wh1hi = (ushort*)alloc((size_t)512*128*2); ushort* wh1lo = (ushort*)alloc((size_t)512*128*2);
  ushort* w12hi = (ushort*)alloc((size_t)512*128*2); ushort* w12lo = (ushort*)alloc((size_t)512*128*2);
  ushort* wh2hi = (ushort*)alloc((size_t)512*128*2); ushort* wh2lo = (ushort*)alloc((size_t)512*128*2);
  ushort* dw1hi = (ushort*)alloc((size_t)384*128*2); ushort* dw1lo = (ushort*)alloc((size_t)384*128*2);
  ushort* encwhi= (ushort*)alloc((size_t)256*512*2); ushort* encwlo= (ushort*)alloc((size_t)256*512*2);
  ushort* w21hi = (ushort*)alloc((size_t)512*256*2); ushort* w21lo = (ushort*)alloc((size_t)512*256*2);
  ushort* wh3hi = (ushort*)alloc((size_t)512*128*2); ushort* wh3lo = (ushort*)alloc((size_t)512*128*2);
  ushort* w22hi = (ushort*)alloc((size_t)512*128*2); ushort* w22lo = (ushort*)alloc((size_t)512*128*2);
  ushort* wh4hi = (ushort*)alloc((size_t)512*128*2); ushort* wh4lo = (ushort*)alloc((size_t)512*128*2);
  ushort* dw2hi = (ushort*)alloc((size_t)256*128*2); ushort* dw2lo = (ushort*)alloc((size_t)256*128*2);
  ushort* decwhi= (ushort*)alloc((size_t)512*256*2); ushort* decwlo= (ushort*)alloc((size_t)512*256*2);
  float* bg1 = (float*)alloc(512*4); float* bg2 = (float*)alloc(512*4);
  float* bm1 = (float*)alloc(384*4);
  float* bg3 = (float*)alloc(512*4); float* bg4 = (float*)alloc(512*4);
  float* bm2 = (float*)alloc(256*4);
  (void)ws_size; (void)in_sizes; (void)n_in; (void)out_size;

  // region overlays
  ushort* maghi  = (ushort*)R1;                              // [BN][288]
  ushort* maglo  = (ushort*)(R1 + (size_t)BN * 288 * 2);
  float*  ENC    = (float*)R1;                               // [BN][256] (MAG dead)
  ushort* ENCNhi = (ushort*)(R1 + (size_t)BN * NE * 4);      // [BN][256]
  ushort* ENCNlo = (ushort*)(R1 + (size_t)BN * NE * 4 + (size_t)BN * NE * 2);
  ushort* Dhi    = ENCNhi;                                   // dec-in planes (ENCN dead)
  ushort* Dlo    = ENCNlo;
  ushort* Y1hi   = (ushort*)G;                               // [BN][512] (gates dead)
  ushort* Y1lo   = (ushort*)G + (size_t)BN * 512;

  const dim3 blk(256);
  auto ceilb = [](long n){ return (int)((n + 255) / 256); };

  // ---- prep: twiddles, weights, biases ----
  fill_fwd<<<ceilb((long)512*512), blk, 0, stream>>>(fwdThi, fwdTlo);
  fill_inv<<<ceilb((long)512*544), blk, 0, stream>>>(invThi, invTlo);
  wconv<<<ceilb((long)512*288), blk, 0, stream>>>(s1_wih1, 512, 257, w11hi, w11lo, 512, 288);
  wconv<<<ceilb((long)512*128), blk, 0, stream>>>(s1_whh1, 512, 128, wh1hi, wh1lo, 512, 128);
  wconv<<<ceilb((long)512*128), blk, 0, stream>>>(s1_wih2, 512, 128, w12hi, w12lo, 512, 128);
  wconv<<<ceilb((long)512*128), blk, 0, stream>>>(s1_whh2, 512, 128, wh2hi, wh2lo, 512, 128);
  wconv<<<ceilb((long)384*128), blk, 0, stream>>>(s1_dw,   257, 128, dw1hi, dw1lo, 384, 128);
  wconv<<<ceilb((long)256*512), blk, 0, stream>>>(enc_w,   256, 512, encwhi, encwlo, 256, 512);
  wconv<<<ceilb((long)512*256), blk, 0, stream>>>(s2_wih1, 512, 256, w21hi, w21lo, 512, 256);
  wconv<<<ceilb((long)512*128), blk, 0, stream>>>(s2_whh1, 512, 128, wh3hi, wh3lo, 512, 128);
  wconv<<<ceilb((long)512*128), blk, 0, stream>>>(s2_wih2, 512, 128, w22hi, w22lo, 512, 128);
  wconv<<<ceilb((long)512*128), blk, 0, stream>>>(s2_whh2, 512, 128, wh4hi, wh4lo, 512, 128);
  wconv<<<ceilb((long)256*128), blk, 0, stream>>>(s2_dw,   256, 128, dw2hi, dw2lo, 256, 128);
  wconv<<<ceilb((long)512*256), blk, 0, stream>>>(dec_w,   512, 256, decwhi, decwlo, 512, 256);
  bias_pad<<<2, blk, 0, stream>>>(s1_bih1, s1_bhh1, 512, bg1, 512);
  bias_pad<<<2, blk, 0, stream>>>(s1_bih2, s1_bhh2, 512, bg2, 512);
  bias_pad<<<2, blk, 0, stream>>>(s1_db,   nullptr, 257, bm1, 384);
  bias_pad<<<2, blk, 0, stream>>>(s2_bih1, s2_bhh1, 512, bg3, 512);
  bias_pad<<<2, blk, 0, stream>>>(s2_bih2, s2_bhh2, 512, bg4, 512);
  bias_pad<<<1, blk, 0, stream>>>(s2_db,   nullptr, 256, bm2, 256);

  convert_x<<<ceilb((long)BN*544), blk, 0, stream>>>(x, XShi, XSlo);
  unpack_state<<<ceilb((long)BN*NH), blk, 0, stream>>>(st1, h1hi, h1lo, C1, h2hi, h2lo, C2);

  // ---- rfft (bins 0..255) + Nyquist ----
  mfma_gemm<<<dim3(128,4), blk, 0, stream>>>(XShi, XSlo, 544, 512,
      fwdThi, fwdTlo, nullptr, nullptr, 0, 0, nullptr, nullptr,
      nullptr, RI, nullptr, nullptr, 514);
  nyq_kernel<<<BN/4, blk, 0, stream>>>(x, RI);
  magphase_kernel<<<ceilb((long)BN*288), blk, 0, stream>>>(RI, maghi, maglo);

  // ---- sep block 1 ----
  mfma_gemm<<<dim3(128,4), blk, 0, stream>>>(maghi, maglo, 288, 288,
      w11hi, w11lo, h1hi, h1lo, 128, 128, wh1hi, wh1lo,
      bg1, G, nullptr, nullptr, 512);
  lstm_cell<<<ceilb((long)BN*NH), blk, 0, stream>>>(G, C1, h1hi, h1lo, out_st1);
  mfma_gemm<<<dim3(128,4), blk, 0, stream>>>(h1hi, h1lo, 128, 128,
      w12hi, w12lo, h2hi, h2lo, 128, 128, wh2hi, wh2lo,
      bg2, G, nullptr, nullptr, 512);
  lstm_cell<<<ceilb((long)BN*NH), blk, 0, stream>>>(G, C2, h2hi, h2lo, out_st1 + (size_t)BN*NH*2);
  mfma_gemm<<<dim3(128,3), blk, 0, stream>>>(h2hi, h2lo, 128, 128,
      dw1hi, dw1lo, nullptr, nullptr, 0, 0, nullptr, nullptr,
      bm1, G, nullptr, nullptr, 512);
  est_build<<<ceilb((long)BN*272), blk, 0, stream>>>(G, 512, maghi, maglo, RI, XShi, XSlo);

  // ---- irfft -> Y1 planes (in G region) ----
  mfma_gemm<<<dim3(128,4), blk, 0, stream>>>(XShi, XSlo, 544, 544,
      invThi, invTlo, nullptr, nullptr, 0, 0, nullptr, nullptr,
      nullptr, nullptr, Y1hi, Y1lo, 512);

  // ---- encoder + LN ----
  mfma_gemm<<<dim3(128,2), blk, 0, stream>>>(Y1hi, Y1lo, 512, 512,
      encwhi, encwlo, nullptr, nullptr, 0, 0, nullptr, nullptr,
      nullptr, ENC, nullptr, nullptr, 256);
  ln_kernel<<<BN, 64, 0, stream>>>(ENC, ln_g, ln_b, ENCNhi, ENCNlo);

  // ---- sep block 2 ----
  unpack_state<<<ceilb((long)BN*NH), blk, 0, stream>>>(st2, h1hi, h1lo, C1, h2hi, h2lo, C2);
  mfma_gemm<<<dim3(128,4), blk, 0, stream>>>(ENCNhi, ENCNlo, 256, 256,
      w21hi, w21lo, h1hi, h1lo, 128, 128, wh3hi, wh3lo,
      bg3, G, nullptr, nullptr, 512);
  lstm_cell<<<ceilb((long)BN*NH), blk, 0, stream>>>(G, C1, h1hi, h1lo, out_st2);
  mfma_gemm<<<dim3(128,4), blk, 0, stream>>>(h1hi, h1lo, 128, 128,
      w22hi, w22lo, h2hi, h2lo, 128, 128, wh4hi, wh4lo,
      bg4, G, nullptr, nullptr, 512);
  lstm_cell<<<ceilb((long)BN*NH), blk, 0, stream>>>(G, C2, h2hi, h2lo, out_st2 + (size_t)BN*NH*2);
  mfma_gemm<<<dim3(128,2), blk, 0, stream>>>(h2hi, h2lo, 128, 128,
      dw2hi, dw2lo, nullptr, nullptr, 0, 0, nullptr, nullptr,
      bm2, G, nullptr, nullptr, 512);

  // ---- decoder ----
  dec_in<<<ceilb((long)BN*NE), blk, 0, stream>>>(G, ENC, Dhi, Dlo);
  mfma_gemm<<<dim3(128,4), blk, 0, stream>>>(Dhi, Dlo, 256, 256,
      decwhi, decwlo, nullptr, nullptr, 0, 0, nullptr, nullptr,
      nullptr, out_dec, nullptr, nullptr, 512);
}